// Round 4
// baseline (13286.560 us; speedup 1.0000x reference)
//
#include <hip/hip_runtime.h>
#include <hip/hip_fp16.h>

typedef unsigned short u16;
typedef _Float16 f16x8 __attribute__((ext_vector_type(8)));
typedef float f32x4 __attribute__((ext_vector_type(4)));

#define VV   96
#define DD   256
#define NSL  24
#define HH   512
#define LL   2
#define BB   64
#define TT   128
#define GHS  776   // padded gh16 row stride in u16

__device__ __forceinline__ u16 f2h(float f){ return __half_as_ushort(__float2half(f)); }
__device__ __forceinline__ float h2f(u16 u){ return __half2float(__ushort_as_half(u)); }
__device__ __forceinline__ float gelu_f(float x){ return 0.5f*x*(1.f+erff(x*0.70710678118654752f)); }
__device__ __forceinline__ float sigm_f(float x){ return 1.f/(1.f+__expf(-x)); }
__device__ __forceinline__ float tanh_f(float x){
  x = fminf(15.f, fmaxf(-15.f, x));
  float e2 = __expf(2.f*x);
  return (e2-1.f)/(e2+1.f);
}

// cache lane g's K/8 slice of vector v (LDS) into registers: NX chunks of 8 floats
template<int NX>
__device__ __forceinline__ void loadx(float4 (&xr)[NX][2], const float* __restrict__ v, int g){
  #pragma unroll
  for(int it=0; it<NX; ++it){
    int k = (it*8 + g)*8;
    xr[it][0] = *(const float4*)(v + k);
    xr[it][1] = *(const float4*)(v + k + 4);
  }
}
// dot of weight row chunk with cached x registers (first ITERS chunks)
template<int ITERS, int NX>
__device__ __forceinline__ float dotw(const u16* __restrict__ row, const float4 (&xr)[NX][2], int g){
  float acc = 0.f;
  #pragma unroll
  for(int it=0; it<ITERS; ++it){
    int k = (it*8 + g)*8;
    uint4 w = *(const uint4*)(row + k);
    float2 f0 = __half22float2(*(const __half2*)&w.x);
    float2 f1 = __half22float2(*(const __half2*)&w.y);
    float2 f2_ = __half22float2(*(const __half2*)&w.z);
    float2 f3 = __half22float2(*(const __half2*)&w.w);
    const float4 a = xr[it][0], bq = xr[it][1];
    acc += f0.x*a.x + f0.y*a.y + f1.x*a.z + f1.y*a.w;
    acc += f2_.x*bq.x + f2_.y*bq.y + f3.x*bq.z + f3.y*bq.w;
  }
  return acc;
}
__device__ __forceinline__ float red8(float acc){
  acc += __shfl_down(acc,4,64);
  acc += __shfl_down(acc,2,64);
  acc += __shfl_down(acc,1,64);
  return acc;
}

// ---------- prep kernels: fp32 -> f16, optionally transposed ----------
__global__ void k_cvt(const float* __restrict__ s, u16* __restrict__ d, int n){
  int i = blockIdx.x*256 + threadIdx.x;
  if(i<n) d[i] = f2h(s[i]);
}
// src [K][N] -> dst [N][K]
__global__ void k_cvtT(const float* __restrict__ s, u16* __restrict__ d, int K, int N){
  int i = blockIdx.x*256 + threadIdx.x;
  if(i < K*N){ int k = i/N, n = i - k*N; d[n*K + k] = f2h(s[i]); }
}

// ---------- LN over 256 elems, 1024 threads (16 waves) ----------
__device__ __forceinline__ void layernorm256(float* __restrict__ dst, const float* __restrict__ src,
    const float* __restrict__ g, const float* __restrict__ bta, float* __restrict__ red, int tid){
  float v = (tid < DD) ? src[tid] : 0.f;
  float s1 = v, s2 = v*v;
  #pragma unroll
  for(int o=32;o>0;o>>=1){ s1 += __shfl_down(s1,o,64); s2 += __shfl_down(s2,o,64); }
  if((tid&63)==0){ red[tid>>6] = s1; red[16+(tid>>6)] = s2; }
  __syncthreads();
  if(tid==0){
    float a=0.f,c=0.f;
    #pragma unroll
    for(int i=0;i<4;++i){ a+=red[i]; c+=red[16+i]; }   // only waves 0-3 hold data
    float m = a*(1.f/DD);
    float var = c*(1.f/DD) - m*m;
    red[32]=m; red[33]=rsqrtf(var+1e-5f);
  }
  __syncthreads();
  if(tid<DD) dst[tid] = (src[tid]-red[32])*red[33]*g[tid] + bta[tid];
  __syncthreads();
}

__global__ __launch_bounds__(1024) void ssr_main(
    const int* __restrict__ x, const float* __restrict__ emb, const float* __restrict__ pos,
    const u16* __restrict__ r1T, const float* __restrict__ b_r1,
    const u16* __restrict__ r2T, const float* __restrict__ b_r2,
    const u16* __restrict__ wihW, const u16* __restrict__ whhW,
    const float* __restrict__ bih, const float* __restrict__ bhh,
    const u16* __restrict__ pjT, const float* __restrict__ b_pj,
    const float* __restrict__ g1, const float* __restrict__ be1,
    const u16* __restrict__ f1T, const float* __restrict__ b_f1,
    const u16* __restrict__ f2T, const float* __restrict__ b_f2,
    const float* __restrict__ g2, const float* __restrict__ be2,
    const float* __restrict__ go, const float* __restrict__ bo,
    const u16* __restrict__ hdT, const float* __restrict__ b_hd,
    float* __restrict__ out)
{
  extern __shared__ float sm[];
  float* S    = sm;            // 12288
  float* gx   = sm + 12288;    // 768
  float* xv   = sm + 13056;    // 256
  float* ctx  = sm + 13312;    // 512
  float* hmid = sm + 13824;    // 256
  float* alpha= sm + 14080;    // 32
  float* sctx = sm + 14112;    // 256
  float* xm   = sm + 14368;    // 256
  float* h1   = sm + 14624;    // 256
  float* ff   = sm + 14880;    // 512
  float* red  = sm + 15392;    // 64
  float* pc   = sm + 15456;    // 1024 (GRU slot_ctx partials)
  u16*  gh16  = (u16*)(sm + 16480); // 24*GHS = 18624 u16 = 9312 floats
  u16*  sbf   = (u16*)(sm + 25792); // 32*264 = 8448 u16 = 4224 floats
  // total 30016 floats = 120064 B

  const int b = blockIdx.x;
  const int tid = threadIdx.x;
  const int g = tid & 7, gid = tid >> 3;   // 128 groups of 8 lanes

  for(int i=tid;i<LL*NSL*DD;i+=1024) S[i]=0.f;
  __syncthreads();

  for(int t=0;t<TT;++t){
    const int tok = x[b*TT + t];
    for(int d=tid; d<DD; d+=1024) xv[d] = emb[tok*DD+d] + pos[t*DD+d];
    __syncthreads();

    for(int li=0; li<LL; ++li){
      float* Sl = S + li*NSL*DD;
      // ---- phase A: ctx = [xv, slot_mean(S_prev)]
      if(tid < DD){
        float s_=0.f;
        #pragma unroll
        for(int j=0;j<NSL;++j) s_ += Sl[j*DD+tid];
        ctx[DD+tid] = s_ * (1.f/NSL);
        ctx[tid] = xv[tid];
      }
      __syncthreads();
      // ---- phase B: route1 (K=512) + gx (K=256, shares xv = ctx[0:256] cache)
      {
        float4 xr[8][2];
        loadx<8>(xr, ctx, g);
        #pragma unroll
        for(int p=0;p<2;++p){
          int d = p*128 + gid;
          const u16* row = r1T + (size_t)(li*DD + d)*(2*DD);
          float acc = red8(dotw<8>(row, xr, g));
          if(!g) hmid[d] = gelu_f(acc + b_r1[li*DD+d]);
        }
        const u16* W = wihW + (size_t)li*3*DD*DD;
        #pragma unroll
        for(int p=0;p<6;++p){
          int n = p*128 + gid;
          float acc = red8(dotw<4>(W + (size_t)n*DD, xr, g));
          if(!g) gx[n] = acc;
        }
      }
      __syncthreads();
      // ---- phase C: route2 (24 outs, K=256) + S->f16 conversion
      {
        if(gid < NSL){
          float4 xh[4][2];
          loadx<4>(xh, hmid, g);
          const u16* row = r2T + (size_t)(li*NSL + gid)*DD;
          float acc = red8(dotw<4>(row, xh, g));
          if(!g) alpha[gid] = acc + b_r2[li*NSL+gid];
        }
        for(int i=tid; i<32*DD; i+=1024){
          int s_ = i>>8, d = i & (DD-1);
          sbf[s_*264+d] = (s_<NSL) ? f2h(Sl[s_*DD+d]) : (u16)0;
        }
      }
      __syncthreads();
      if(tid==0){ // softmax over 24 (TAU=1); consumed after phase-D barrier
        float m=-1e30f;
        for(int s_=0;s_<NSL;++s_) m = fmaxf(m, alpha[s_]);
        float sum=0.f;
        for(int s_=0;s_<NSL;++s_){ float e=__expf(alpha[s_]-m); alpha[s_]=e; sum+=e; }
        float inv = 1.f/sum;
        for(int s_=0;s_<NSL;++s_) alpha[s_]*=inv;
      }
      // ---- phase D: gh = S @ whh^T via mfma 16x16x32 f16 (16 waves, 3 tiles each)
      {
        const int l = tid & 63, w = tid >> 6;
        const int lr = l & 15, lk = l >> 4;
        const u16* WB = whhW + (size_t)li*3*DD*DD;
        const u16* a0p = sbf + lr*264 + lk*8;
        const u16* a1p = sbf + (16+lr)*264 + lk*8;
        for(int nt=w; nt<48; nt+=16){
          const u16* bp = WB + (size_t)(nt*16 + lr)*DD + lk*8;
          f32x4 acc0 = {0.f,0.f,0.f,0.f}, acc1 = {0.f,0.f,0.f,0.f};
          #pragma unroll
          for(int ks=0; ks<8; ++ks){
            f16x8 bfr = *(const f16x8*)(bp + ks*32);
            f16x8 a0  = *(const f16x8*)(a0p + ks*32);
            f16x8 a1  = *(const f16x8*)(a1p + ks*32);
            acc0 = __builtin_amdgcn_mfma_f32_16x16x32_f16(a0, bfr, acc0, 0,0,0);
            acc1 = __builtin_amdgcn_mfma_f32_16x16x32_f16(a1, bfr, acc1, 0,0,0);
          }
          #pragma unroll
          for(int r=0;r<4;++r){
            int s0 = lk*4 + r;                 // row=(lane>>4)*4+reg, col=lane&15
            gh16[s0*GHS + nt*16 + lr] = f2h(acc0[r]);
            int s1 = 16 + lk*4 + r;
            if(s1 < NSL) gh16[s1*GHS + nt*16 + lr] = f2h(acc1[r]);
          }
        }
      }
      __syncthreads();
      // ---- phase E: GRU update + slot_ctx partials (4 sub-banks of 256 threads)
      {
        int d = tid & (DD-1), so = tid >> 8;   // so in [0,4)
        const float* bihL = bih + li*3*DD;
        const float* bhhL = bhh + li*3*DD;
        float gir = gx[d], giz = gx[DD+d], gin = gx[2*DD+d];
        float bir = bihL[d], biz = bihL[DD+d], bin = bihL[2*DD+d];
        float bhr = bhhL[d], bhz = bhhL[DD+d], bhn = bhhL[2*DD+d];
        float pctx = 0.f;
        for(int j=0;j<NSL/4;++j){
          int s_ = 4*j + so;
          float al = alpha[s_];
          float hr = h2f(gh16[s_*GHS+d])      + bhr;
          float hz = h2f(gh16[s_*GHS+DD+d])   + bhz;
          float hn = h2f(gh16[s_*GHS+2*DD+d]) + bhn;
          float rr = sigm_f(al*gir + bir + hr);
          float zz = sigm_f(al*giz + biz + hz);
          float nn = tanh_f(al*gin + bin + rr*hn);
          float sv = Sl[s_*DD+d];
          float ns = (1.f-zz)*nn + zz*sv;
          Sl[s_*DD+d] = ns;
          pctx += al*ns;
        }
        pc[tid] = pctx;
      }
      __syncthreads();
      if(tid<DD) sctx[tid] = pc[tid] + pc[DD+tid] + pc[2*DD+tid] + pc[3*DD+tid];
      __syncthreads();
      // ---- phase F: proj [256 outs, K=256]
      {
        float4 xs[4][2];
        loadx<4>(xs, sctx, g);
        #pragma unroll
        for(int p=0;p<2;++p){
          int d = p*128 + gid;
          const u16* row = pjT + (size_t)(li*DD + d)*DD;
          float acc = red8(dotw<4>(row, xs, g));
          if(!g) xm[d] = xv[d] + b_pj[li*DD+d] + acc;
        }
      }
      __syncthreads();
      // ---- LN1
      layernorm256(h1, xm, g1+li*DD, be1+li*DD, red, tid);
      // ---- ffn1 [512 outs, K=256]
      {
        float4 xh[4][2];
        loadx<4>(xh, h1, g);
        #pragma unroll
        for(int p=0;p<4;++p){
          int n = p*128 + gid;
          const u16* row = f1T + (size_t)(li*HH + n)*DD;
          float acc = red8(dotw<4>(row, xh, g));
          if(!g) ff[n] = gelu_f(acc + b_f1[li*HH+n]);
        }
      }
      __syncthreads();
      // ---- ffn2 [256 outs, K=512]
      {
        float4 xf[8][2];
        loadx<8>(xf, ff, g);
        #pragma unroll
        for(int p=0;p<2;++p){
          int d = p*128 + gid;
          const u16* row = f2T + (size_t)(li*DD + d)*HH;
          float acc = red8(dotw<8>(row, xf, g));
          if(!g) xm[d] = xm[d] + b_f2[li*DD+d] + acc;
        }
      }
      __syncthreads();
      // ---- LN2 -> xv (next layer input)
      layernorm256(xv, xm, g2+li*DD, be2+li*DD, red, tid);
    } // layers

    // ---- head: LN + [96 x 256] GEMV
    layernorm256(h1, xv, go, bo, red, tid);
    if(gid < VV){
      float4 xh[4][2];
      loadx<4>(xh, h1, g);
      float acc = red8(dotw<4>(hdT + (size_t)gid*DD, xh, g));
      if(!g) out[((size_t)b*TT + t)*VV + gid] = acc + b_hd[gid];
    }
    __syncthreads();
  }
}

extern "C" void kernel_launch(void* const* d_in, const int* in_sizes, int n_in,
                              void* d_out, int out_size, void* d_ws, size_t ws_size,
                              hipStream_t stream){
  const int*   x    = (const int*)  d_in[0];
  const float* emb  = (const float*)d_in[1];
  const float* pos  = (const float*)d_in[2];
  const float* r1   = (const float*)d_in[3];
  const float* br1  = (const float*)d_in[4];
  const float* r2   = (const float*)d_in[5];
  const float* br2  = (const float*)d_in[6];
  const float* wih  = (const float*)d_in[7];
  const float* whh  = (const float*)d_in[8];
  const float* bih  = (const float*)d_in[9];
  const float* bhh  = (const float*)d_in[10];
  const float* pj   = (const float*)d_in[11];
  const float* bpj  = (const float*)d_in[12];
  const float* g1   = (const float*)d_in[13];
  const float* be1  = (const float*)d_in[14];
  const float* f1   = (const float*)d_in[15];
  const float* bf1  = (const float*)d_in[16];
  const float* f2   = (const float*)d_in[17];
  const float* bf2  = (const float*)d_in[18];
  const float* g2   = (const float*)d_in[19];
  const float* be2  = (const float*)d_in[20];
  const float* go   = (const float*)d_in[21];
  const float* bo   = (const float*)d_in[22];
  const float* hd   = (const float*)d_in[23];
  const float* bhd  = (const float*)d_in[24];
  float* out = (float*)d_out;
  u16* ws = (u16*)d_ws;

  // f16 weight sections in workspace (element offsets)
  u16* r1T  = ws + 0;        // L*256*512
  u16* r2T  = ws + 262144;   // L*24*256
  u16* wihW = ws + 274432;   // L*768*256
  u16* whhW = ws + 667648;   // L*768*256
  u16* pjT  = ws + 1060864;  // L*256*256
  u16* f1T  = ws + 1191936;  // L*512*256
  u16* f2T  = ws + 1454080;  // L*256*512
  u16* hdT  = ws + 1716224;  // 96*256

  k_cvt<<<(2*768*256+255)/256,256,0,stream>>>(wih, wihW, 2*768*256);
  k_cvt<<<(2*768*256+255)/256,256,0,stream>>>(whh, whhW, 2*768*256);
  for(int li=0; li<2; ++li){
    k_cvtT<<<(512*256+255)/256,256,0,stream>>>(r1 + li*512*256, r1T + li*256*512, 512, 256);
    k_cvtT<<<(256*24+255)/256, 256,0,stream>>>(r2 + li*256*24,  r2T + li*24*256,  256, 24);
    k_cvtT<<<(256*256+255)/256,256,0,stream>>>(pj + li*256*256, pjT + li*256*256, 256, 256);
    k_cvtT<<<(256*512+255)/256,256,0,stream>>>(f1 + li*256*512, f1T + li*512*256, 256, 512);
    k_cvtT<<<(512*256+255)/256,256,0,stream>>>(f2 + li*512*256, f2T + li*256*512, 512, 256);
  }
  k_cvtT<<<(256*96+255)/256,256,0,stream>>>(hd, hdT, 256, 96);

  const int smem = 30016*4;
  hipFuncSetAttribute(reinterpret_cast<const void*>(ssr_main),
                      hipFuncAttributeMaxDynamicSharedMemorySize, smem);
  ssr_main<<<BB, 1024, smem, stream>>>(x, emb, pos, r1T, br1, r2T, br2, wihW, whhW, bih, bhh,
                                       pjT, bpj, g1, be1, f1T, bf1, f2T, bf2, g2, be2, go, bo,
                                       hdT, bhd, out);
}

// Round 5
// 8484.412 us; speedup vs baseline: 1.5660x; 1.5660x over previous
//
#include <hip/hip_runtime.h>
#include <hip/hip_fp16.h>

typedef unsigned short u16;
typedef _Float16 f16x8 __attribute__((ext_vector_type(8)));
typedef float f32x4 __attribute__((ext_vector_type(4)));

#define VV   96
#define DD   256
#define NSL  24
#define HH   512
#define LL   2
#define BB   64
#define TT   128
#define GHS  776   // padded gh16 row stride in u16

__device__ __forceinline__ u16 f2h(float f){ return __half_as_ushort(__float2half(f)); }
__device__ __forceinline__ float h2f(u16 u){ return __half2float(__ushort_as_half(u)); }
__device__ __forceinline__ float gelu_f(float x){ return 0.5f*x*(1.f+erff(x*0.70710678118654752f)); }
__device__ __forceinline__ float sigm_f(float x){ return 1.f/(1.f+__expf(-x)); }
__device__ __forceinline__ float tanh_f(float x){
  x = fminf(15.f, fmaxf(-15.f, x));
  float e2 = __expf(2.f*x);
  return (e2-1.f)/(e2+1.f);
}

// grouped GEMV: 8 lanes per output row, lane g reads 16B chunk (it*8+g)*8.
// x read directly from LDS (8-way broadcast across groups, conflict-free).
__device__ __forceinline__ float dotg8(const u16* __restrict__ row, const float* __restrict__ v,
                                       int g, int iters){
  float acc = 0.f;
  #pragma unroll
  for(int it=0; it<iters; ++it){
    int k = (it*8 + g)*8;
    uint4 w = *(const uint4*)(row + k);
    float4 a  = *(const float4*)(v + k);
    float4 bq = *(const float4*)(v + k + 4);
    float2 f0 = __half22float2(*(const __half2*)&w.x);
    float2 f1 = __half22float2(*(const __half2*)&w.y);
    float2 f2_ = __half22float2(*(const __half2*)&w.z);
    float2 f3 = __half22float2(*(const __half2*)&w.w);
    acc += f0.x*a.x + f0.y*a.y + f1.x*a.z + f1.y*a.w;
    acc += f2_.x*bq.x + f2_.y*bq.y + f3.x*bq.z + f3.y*bq.w;
  }
  return acc;
}
__device__ __forceinline__ float red8(float acc){
  acc += __shfl_down(acc,4,64);
  acc += __shfl_down(acc,2,64);
  acc += __shfl_down(acc,1,64);
  return acc;
}

// ---------- prep kernels: fp32 -> f16, optionally transposed ----------
__global__ void k_cvt(const float* __restrict__ s, u16* __restrict__ d, int n){
  int i = blockIdx.x*256 + threadIdx.x;
  if(i<n) d[i] = f2h(s[i]);
}
// src [K][N] -> dst [N][K]
__global__ void k_cvtT(const float* __restrict__ s, u16* __restrict__ d, int K, int N){
  int i = blockIdx.x*256 + threadIdx.x;
  if(i < K*N){ int k = i/N, n = i - k*N; d[n*K + k] = f2h(s[i]); }
}

// ---------- LN over 256 elems, 1024 threads (16 waves) ----------
__device__ __forceinline__ void layernorm256(float* __restrict__ dst, const float* __restrict__ src,
    const float* __restrict__ g, const float* __restrict__ bta, float* __restrict__ red, int tid){
  float v = (tid < DD) ? src[tid] : 0.f;
  float s1 = v, s2 = v*v;
  #pragma unroll
  for(int o=32;o>0;o>>=1){ s1 += __shfl_down(s1,o,64); s2 += __shfl_down(s2,o,64); }
  if((tid&63)==0){ red[tid>>6] = s1; red[16+(tid>>6)] = s2; }
  __syncthreads();
  if(tid==0){
    float a=0.f,c=0.f;
    #pragma unroll
    for(int i=0;i<4;++i){ a+=red[i]; c+=red[16+i]; }   // only waves 0-3 hold data
    float m = a*(1.f/DD);
    float var = c*(1.f/DD) - m*m;
    red[32]=m; red[33]=rsqrtf(var+1e-5f);
  }
  __syncthreads();
  if(tid<DD) dst[tid] = (src[tid]-red[32])*red[33]*g[tid] + bta[tid];
  __syncthreads();
}

__global__ __launch_bounds__(1024, 4) void ssr_main(
    const int* __restrict__ x, const float* __restrict__ emb, const float* __restrict__ pos,
    const u16* __restrict__ r1T, const float* __restrict__ b_r1,
    const u16* __restrict__ r2T, const float* __restrict__ b_r2,
    const u16* __restrict__ wihW, const u16* __restrict__ whhW,
    const float* __restrict__ bih, const float* __restrict__ bhh,
    const u16* __restrict__ pjT, const float* __restrict__ b_pj,
    const float* __restrict__ g1, const float* __restrict__ be1,
    const u16* __restrict__ f1T, const float* __restrict__ b_f1,
    const u16* __restrict__ f2T, const float* __restrict__ b_f2,
    const float* __restrict__ g2, const float* __restrict__ be2,
    const float* __restrict__ go, const float* __restrict__ bo,
    const u16* __restrict__ hdT, const float* __restrict__ b_hd,
    float* __restrict__ out)
{
  extern __shared__ float sm[];
  float* S    = sm;            // 12288
  float* gx   = sm + 12288;    // 768
  float* xv   = sm + 13056;    // 256
  float* ctx  = sm + 13312;    // 512
  float* hmid = sm + 13824;    // 256
  float* alpha= sm + 14080;    // 32
  float* sctx = sm + 14112;    // 256
  float* xm   = sm + 14368;    // 256
  float* h1   = sm + 14624;    // 256
  float* ff   = sm + 14880;    // 512
  float* red  = sm + 15392;    // 64
  float* pc   = sm + 15456;    // 1024 (GRU slot_ctx partials)
  u16*  gh16  = (u16*)(sm + 16480); // 24*GHS = 18624 u16 = 9312 floats
  u16*  sbf   = (u16*)(sm + 25792); // 32*264 = 8448 u16 = 4224 floats
  // total 30016 floats = 120064 B

  const int b = blockIdx.x;
  const int tid = threadIdx.x;
  const int g = tid & 7, gid = tid >> 3;   // 128 groups of 8 lanes

  for(int i=tid;i<LL*NSL*DD;i+=1024) S[i]=0.f;
  __syncthreads();

  for(int t=0;t<TT;++t){
    const int tok = x[b*TT + t];
    for(int d=tid; d<DD; d+=1024) xv[d] = emb[tok*DD+d] + pos[t*DD+d];
    __syncthreads();

    for(int li=0; li<LL; ++li){
      float* Sl = S + li*NSL*DD;
      // ---- phase A: ctx = [xv, slot_mean(S_prev)]
      if(tid < DD){
        float s_=0.f;
        #pragma unroll
        for(int j=0;j<NSL;++j) s_ += Sl[j*DD+tid];
        ctx[DD+tid] = s_ * (1.f/NSL);
        ctx[tid] = xv[tid];
      }
      __syncthreads();
      // ---- phase B: route1 (256 outs, K=512) + gx (768 outs, K=256)
      {
        #pragma unroll
        for(int p=0;p<2;++p){
          int d = p*128 + gid;
          const u16* row = r1T + (size_t)(li*DD + d)*(2*DD);
          float acc = red8(dotg8(row, ctx, g, 8));
          if(!g) hmid[d] = gelu_f(acc + b_r1[li*DD+d]);
        }
        const u16* W = wihW + (size_t)li*3*DD*DD;
        #pragma unroll 3
        for(int p=0;p<6;++p){
          int n = p*128 + gid;
          float acc = red8(dotg8(W + (size_t)n*DD, xv, g, 4));
          if(!g) gx[n] = acc;
        }
      }
      __syncthreads();
      // ---- phase C: route2 (24 outs, K=256) + S->f16 conversion
      {
        if(gid < NSL){
          const u16* row = r2T + (size_t)(li*NSL + gid)*DD;
          float acc = red8(dotg8(row, hmid, g, 4));
          if(!g) alpha[gid] = acc + b_r2[li*NSL+gid];
        }
        for(int i=tid; i<32*DD; i+=1024){
          int s_ = i>>8, d = i & (DD-1);
          sbf[s_*264+d] = (s_<NSL) ? f2h(Sl[s_*DD+d]) : (u16)0;
        }
      }
      __syncthreads();
      if(tid==0){ // softmax over 24 (TAU=1); consumed after phase-D barrier
        float m=-1e30f;
        for(int s_=0;s_<NSL;++s_) m = fmaxf(m, alpha[s_]);
        float sum=0.f;
        for(int s_=0;s_<NSL;++s_){ float e=__expf(alpha[s_]-m); alpha[s_]=e; sum+=e; }
        float inv = 1.f/sum;
        for(int s_=0;s_<NSL;++s_) alpha[s_]*=inv;
      }
      // ---- phase D: gh = S @ whh^T via mfma 16x16x32 f16 (16 waves, 3 tiles each)
      {
        const int l = tid & 63, w = tid >> 6;
        const int lr = l & 15, lk = l >> 4;
        const u16* WB = whhW + (size_t)li*3*DD*DD;
        const u16* a0p = sbf + lr*264 + lk*8;
        const u16* a1p = sbf + (16+lr)*264 + lk*8;
        for(int nt=w; nt<48; nt+=16){
          const u16* bp = WB + (size_t)(nt*16 + lr)*DD + lk*8;
          f32x4 acc0 = {0.f,0.f,0.f,0.f}, acc1 = {0.f,0.f,0.f,0.f};
          #pragma unroll
          for(int ks=0; ks<8; ++ks){
            f16x8 bfr = *(const f16x8*)(bp + ks*32);
            f16x8 a0  = *(const f16x8*)(a0p + ks*32);
            f16x8 a1  = *(const f16x8*)(a1p + ks*32);
            acc0 = __builtin_amdgcn_mfma_f32_16x16x32_f16(a0, bfr, acc0, 0,0,0);
            acc1 = __builtin_amdgcn_mfma_f32_16x16x32_f16(a1, bfr, acc1, 0,0,0);
          }
          #pragma unroll
          for(int r=0;r<4;++r){
            int s0 = lk*4 + r;                 // row=(lane>>4)*4+reg, col=lane&15
            gh16[s0*GHS + nt*16 + lr] = f2h(acc0[r]);
            int s1 = 16 + lk*4 + r;
            if(s1 < NSL) gh16[s1*GHS + nt*16 + lr] = f2h(acc1[r]);
          }
        }
      }
      __syncthreads();
      // ---- phase E: GRU update + slot_ctx partials (4 sub-banks of 256 threads)
      {
        int d = tid & (DD-1), so = tid >> 8;   // so in [0,4)
        const float* bihL = bih + li*3*DD;
        const float* bhhL = bhh + li*3*DD;
        float gir = gx[d], giz = gx[DD+d], gin = gx[2*DD+d];
        float bir = bihL[d], biz = bihL[DD+d], bin = bihL[2*DD+d];
        float bhr = bhhL[d], bhz = bhhL[DD+d], bhn = bhhL[2*DD+d];
        float pctx = 0.f;
        for(int j=0;j<NSL/4;++j){
          int s_ = 4*j + so;
          float al = alpha[s_];
          float hr = h2f(gh16[s_*GHS+d])      + bhr;
          float hz = h2f(gh16[s_*GHS+DD+d])   + bhz;
          float hn = h2f(gh16[s_*GHS+2*DD+d]) + bhn;
          float rr = sigm_f(al*gir + bir + hr);
          float zz = sigm_f(al*giz + biz + hz);
          float nn = tanh_f(al*gin + bin + rr*hn);
          float sv = Sl[s_*DD+d];
          float ns = (1.f-zz)*nn + zz*sv;
          Sl[s_*DD+d] = ns;
          pctx += al*ns;
        }
        pc[tid] = pctx;
      }
      __syncthreads();
      if(tid<DD) sctx[tid] = pc[tid] + pc[DD+tid] + pc[2*DD+tid] + pc[3*DD+tid];
      __syncthreads();
      // ---- phase F: proj [256 outs, K=256]
      {
        #pragma unroll
        for(int p=0;p<2;++p){
          int d = p*128 + gid;
          const u16* row = pjT + (size_t)(li*DD + d)*DD;
          float acc = red8(dotg8(row, sctx, g, 4));
          if(!g) xm[d] = xv[d] + b_pj[li*DD+d] + acc;
        }
      }
      __syncthreads();
      // ---- LN1
      layernorm256(h1, xm, g1+li*DD, be1+li*DD, red, tid);
      // ---- ffn1 [512 outs, K=256]
      {
        #pragma unroll 2
        for(int p=0;p<4;++p){
          int n = p*128 + gid;
          const u16* row = f1T + (size_t)(li*HH + n)*DD;
          float acc = red8(dotg8(row, h1, g, 4));
          if(!g) ff[n] = gelu_f(acc + b_f1[li*HH+n]);
        }
      }
      __syncthreads();
      // ---- ffn2 [256 outs, K=512]
      {
        #pragma unroll
        for(int p=0;p<2;++p){
          int d = p*128 + gid;
          const u16* row = f2T + (size_t)(li*DD + d)*HH;
          float acc = red8(dotg8(row, ff, g, 8));
          if(!g) xm[d] = xm[d] + b_f2[li*DD+d] + acc;
        }
      }
      __syncthreads();
      // ---- LN2 -> xv (next layer input)
      layernorm256(xv, xm, g2+li*DD, be2+li*DD, red, tid);
    } // layers

    // ---- head: LN + [96 x 256] GEMV
    layernorm256(h1, xv, go, bo, red, tid);
    if(gid < VV){
      float acc = red8(dotg8(hdT + (size_t)gid*DD, h1, g, 4));
      if(!g) out[((size_t)b*TT + t)*VV + gid] = acc + b_hd[gid];
    }
    __syncthreads();
  }
}

extern "C" void kernel_launch(void* const* d_in, const int* in_sizes, int n_in,
                              void* d_out, int out_size, void* d_ws, size_t ws_size,
                              hipStream_t stream){
  const int*   x    = (const int*)  d_in[0];
  const float* emb  = (const float*)d_in[1];
  const float* pos  = (const float*)d_in[2];
  const float* r1   = (const float*)d_in[3];
  const float* br1  = (const float*)d_in[4];
  const float* r2   = (const float*)d_in[5];
  const float* br2  = (const float*)d_in[6];
  const float* wih  = (const float*)d_in[7];
  const float* whh  = (const float*)d_in[8];
  const float* bih  = (const float*)d_in[9];
  const float* bhh  = (const float*)d_in[10];
  const float* pj   = (const float*)d_in[11];
  const float* bpj  = (const float*)d_in[12];
  const float* g1   = (const float*)d_in[13];
  const float* be1  = (const float*)d_in[14];
  const float* f1   = (const float*)d_in[15];
  const float* bf1  = (const float*)d_in[16];
  const float* f2   = (const float*)d_in[17];
  const float* bf2  = (const float*)d_in[18];
  const float* g2   = (const float*)d_in[19];
  const float* be2  = (const float*)d_in[20];
  const float* go   = (const float*)d_in[21];
  const float* bo   = (const float*)d_in[22];
  const float* hd   = (const float*)d_in[23];
  const float* bhd  = (const float*)d_in[24];
  float* out = (float*)d_out;
  u16* ws = (u16*)d_ws;

  // f16 weight sections in workspace (element offsets)
  u16* r1T  = ws + 0;        // L*256*512
  u16* r2T  = ws + 262144;   // L*24*256
  u16* wihW = ws + 274432;   // L*768*256
  u16* whhW = ws + 667648;   // L*768*256
  u16* pjT  = ws + 1060864;  // L*256*256
  u16* f1T  = ws + 1191936;  // L*512*256
  u16* f2T  = ws + 1454080;  // L*256*512
  u16* hdT  = ws + 1716224;  // 96*256

  k_cvt<<<(2*768*256+255)/256,256,0,stream>>>(wih, wihW, 2*768*256);
  k_cvt<<<(2*768*256+255)/256,256,0,stream>>>(whh, whhW, 2*768*256);
  for(int li=0; li<2; ++li){
    k_cvtT<<<(512*256+255)/256,256,0,stream>>>(r1 + li*512*256, r1T + li*256*512, 512, 256);
    k_cvtT<<<(256*24+255)/256, 256,0,stream>>>(r2 + li*256*24,  r2T + li*24*256,  256, 24);
    k_cvtT<<<(256*256+255)/256,256,0,stream>>>(pj + li*256*256, pjT + li*256*256, 256, 256);
    k_cvtT<<<(256*512+255)/256,256,0,stream>>>(f1 + li*256*512, f1T + li*512*256, 256, 512);
    k_cvtT<<<(512*256+255)/256,256,0,stream>>>(f2 + li*512*256, f2T + li*256*512, 512, 256);
  }
  k_cvtT<<<(256*96+255)/256,256,0,stream>>>(hd, hdT, 256, 96);

  const int smem = 30016*4;
  hipFuncSetAttribute(reinterpret_cast<const void*>(ssr_main),
                      hipFuncAttributeMaxDynamicSharedMemorySize, smem);
  ssr_main<<<BB, 1024, smem, stream>>>(x, emb, pos, r1T, br1, r2T, br2, wihW, whhW, bih, bhh,
                                       pjT, bpj, g1, be1, f1T, bf1, f2T, bf2, g2, be2, go, bo,
                                       hdT, bhd, out);
}

// Round 6
// 7688.735 us; speedup vs baseline: 1.7281x; 1.1035x over previous
//
#include <hip/hip_runtime.h>
#include <hip/hip_fp16.h>

typedef unsigned short u16;
typedef _Float16 f16x8 __attribute__((ext_vector_type(8)));
typedef float f32x4 __attribute__((ext_vector_type(4)));

#define VV   96
#define DD   256
#define NSL  24
#define HH   512
#define LL   2
#define BB   64
#define TT   128
#define GHS  776   // padded gh16 row stride in u16

__device__ __forceinline__ u16 f2h(float f){ return __half_as_ushort(__float2half(f)); }
__device__ __forceinline__ float h2f(u16 u){ return __half2float(__ushort_as_half(u)); }
__device__ __forceinline__ float gelu_f(float x){ return 0.5f*x*(1.f+erff(x*0.70710678118654752f)); }
__device__ __forceinline__ float sigm_f(float x){ return 1.f/(1.f+__expf(-x)); }
__device__ __forceinline__ float tanh_f(float x){
  x = fminf(15.f, fmaxf(-15.f, x));
  float e2 = __expf(2.f*x);
  return (e2-1.f)/(e2+1.f);
}

// two-row grouped GEMV with explicit load batching: issue ALL 2*IT weight
// loads first (registers), then convert+FMA. Raises outstanding misses/thread.
template<int IT>
__device__ __forceinline__ void dot2(const u16* __restrict__ rA, const u16* __restrict__ rB,
                                     const float* __restrict__ v, int g, int kofs,
                                     float& oA, float& oB){
  uint4 wA[IT], wB[IT];
  #pragma unroll
  for(int it=0; it<IT; ++it){
    const int k = kofs + (it*8+g)*8;
    wA[it] = *(const uint4*)(rA + k);
    wB[it] = *(const uint4*)(rB + k);
  }
  float aA = 0.f, aB = 0.f;
  #pragma unroll
  for(int it=0; it<IT; ++it){
    const int k = kofs + (it*8+g)*8;
    const float4 a = *(const float4*)(v + k);
    const float4 b = *(const float4*)(v + k + 4);
    float2 p0 = __half22float2(*(const __half2*)&wA[it].x);
    float2 p1 = __half22float2(*(const __half2*)&wA[it].y);
    float2 p2 = __half22float2(*(const __half2*)&wA[it].z);
    float2 p3 = __half22float2(*(const __half2*)&wA[it].w);
    aA += p0.x*a.x + p0.y*a.y + p1.x*a.z + p1.y*a.w
        + p2.x*b.x + p2.y*b.y + p3.x*b.z + p3.y*b.w;
    float2 q0 = __half22float2(*(const __half2*)&wB[it].x);
    float2 q1 = __half22float2(*(const __half2*)&wB[it].y);
    float2 q2 = __half22float2(*(const __half2*)&wB[it].z);
    float2 q3 = __half22float2(*(const __half2*)&wB[it].w);
    aB += q0.x*a.x + q0.y*a.y + q1.x*a.z + q1.y*a.w
        + q2.x*b.x + q2.y*b.y + q3.x*b.z + q3.y*b.w;
  }
  oA += aA; oB += aB;
}

// single-row variant (small phases)
__device__ __forceinline__ float dotg8(const u16* __restrict__ row, const float* __restrict__ v,
                                       int g, int iters){
  float acc = 0.f;
  #pragma unroll
  for(int it=0; it<iters; ++it){
    int k = (it*8 + g)*8;
    uint4 w = *(const uint4*)(row + k);
    float4 a  = *(const float4*)(v + k);
    float4 bq = *(const float4*)(v + k + 4);
    float2 f0 = __half22float2(*(const __half2*)&w.x);
    float2 f1 = __half22float2(*(const __half2*)&w.y);
    float2 f2_ = __half22float2(*(const __half2*)&w.z);
    float2 f3 = __half22float2(*(const __half2*)&w.w);
    acc += f0.x*a.x + f0.y*a.y + f1.x*a.z + f1.y*a.w;
    acc += f2_.x*bq.x + f2_.y*bq.y + f3.x*bq.z + f3.y*bq.w;
  }
  return acc;
}
__device__ __forceinline__ float red8(float acc){
  acc += __shfl_down(acc,4,64);
  acc += __shfl_down(acc,2,64);
  acc += __shfl_down(acc,1,64);
  return acc;
}

// ---------- prep kernels: fp32 -> f16, optionally transposed ----------
__global__ void k_cvt(const float* __restrict__ s, u16* __restrict__ d, int n){
  int i = blockIdx.x*256 + threadIdx.x;
  if(i<n) d[i] = f2h(s[i]);
}
// src [K][N] -> dst [N][K]
__global__ void k_cvtT(const float* __restrict__ s, u16* __restrict__ d, int K, int N){
  int i = blockIdx.x*256 + threadIdx.x;
  if(i < K*N){ int k = i/N, n = i - k*N; d[n*K + k] = f2h(s[i]); }
}

// ---------- LN over 256 elems, 1024 threads (16 waves) ----------
__device__ __forceinline__ void layernorm256(float* __restrict__ dst, const float* __restrict__ src,
    const float* __restrict__ g, const float* __restrict__ bta, float* __restrict__ red, int tid){
  float v = (tid < DD) ? src[tid] : 0.f;
  float s1 = v, s2 = v*v;
  #pragma unroll
  for(int o=32;o>0;o>>=1){ s1 += __shfl_down(s1,o,64); s2 += __shfl_down(s2,o,64); }
  if((tid&63)==0){ red[tid>>6] = s1; red[16+(tid>>6)] = s2; }
  __syncthreads();
  if(tid==0){
    float a=0.f,c=0.f;
    #pragma unroll
    for(int i=0;i<4;++i){ a+=red[i]; c+=red[16+i]; }   // only waves 0-3 hold data
    float m = a*(1.f/DD);
    float var = c*(1.f/DD) - m*m;
    red[32]=m; red[33]=rsqrtf(var+1e-5f);
  }
  __syncthreads();
  if(tid<DD) dst[tid] = (src[tid]-red[32])*red[33]*g[tid] + bta[tid];
  __syncthreads();
}

__global__ __launch_bounds__(1024, 4) void ssr_main(
    const int* __restrict__ x, const float* __restrict__ emb, const float* __restrict__ pos,
    const u16* __restrict__ r1T, const float* __restrict__ b_r1,
    const u16* __restrict__ r2T, const float* __restrict__ b_r2,
    const u16* __restrict__ wihW, const u16* __restrict__ whhW,
    const float* __restrict__ bih, const float* __restrict__ bhh,
    const u16* __restrict__ pjT, const float* __restrict__ b_pj,
    const float* __restrict__ g1, const float* __restrict__ be1,
    const u16* __restrict__ f1T, const float* __restrict__ b_f1,
    const u16* __restrict__ f2T, const float* __restrict__ b_f2,
    const float* __restrict__ g2, const float* __restrict__ be2,
    const float* __restrict__ go, const float* __restrict__ bo,
    const u16* __restrict__ hdT, const float* __restrict__ b_hd,
    float* __restrict__ out)
{
  extern __shared__ float sm[];
  float* S    = sm;            // 12288
  float* gx   = sm + 12288;    // 768
  float* xv   = sm + 13056;    // 256
  float* ctx  = sm + 13312;    // 512
  float* hmid = sm + 13824;    // 256
  float* alpha= sm + 14080;    // 32
  float* sctx = sm + 14112;    // 256
  float* xm   = sm + 14368;    // 256
  float* h1   = sm + 14624;    // 256
  float* ff   = sm + 14880;    // 512
  float* red  = sm + 15392;    // 64
  float* pc   = sm + 15456;    // 1024 (GRU slot_ctx partials)
  u16*  gh16  = (u16*)(sm + 16480); // 24*GHS = 18624 u16 = 9312 floats
  u16*  sbf   = (u16*)(sm + 25792); // 32*264 = 8448 u16 = 4224 floats
  // total 30016 floats = 120064 B

  const int b = blockIdx.x;
  const int tid = threadIdx.x;
  const int g = tid & 7, gid = tid >> 3;   // 128 groups of 8 lanes

  for(int i=tid;i<LL*NSL*DD;i+=1024) S[i]=0.f;
  __syncthreads();

  for(int t=0;t<TT;++t){
    const int tok = x[b*TT + t];
    for(int d=tid; d<DD; d+=1024) xv[d] = emb[tok*DD+d] + pos[t*DD+d];
    __syncthreads();

    for(int li=0; li<LL; ++li){
      float* Sl = S + li*NSL*DD;
      // ---- phase A: ctx = [xv, slot_mean(S_prev)]
      if(tid < DD){
        float s_=0.f;
        #pragma unroll
        for(int j=0;j<NSL;++j) s_ += Sl[j*DD+tid];
        ctx[DD+tid] = s_ * (1.f/NSL);
        ctx[tid] = xv[tid];
      }
      __syncthreads();
      // ---- phase B: route1 (256 outs, K=512) + gx (768 outs, K=256)
      {
        // route1: rows gid and 128+gid
        float aA=0.f, aB=0.f;
        const u16* rA = r1T + (size_t)(li*DD + gid)*(2*DD);
        const u16* rB = rA + (size_t)128*(2*DD);
        dot2<4>(rA, rB, ctx, g, 0,   aA, aB);
        dot2<4>(rA, rB, ctx, g, 256, aA, aB);
        aA = red8(aA); aB = red8(aB);
        if(!g){
          hmid[gid]     = gelu_f(aA + b_r1[li*DD+gid]);
          hmid[128+gid] = gelu_f(aB + b_r1[li*DD+128+gid]);
        }
        // gx: rows p*128+gid, p in 0..5, pairs (0,1),(2,3),(4,5)
        const u16* W = wihW + (size_t)li*3*DD*DD;
        #pragma unroll
        for(int pp=0; pp<3; ++pp){
          float a0=0.f, a1=0.f;
          const u16* r0 = W + (size_t)(pp*256 + gid)*DD;
          const u16* r1_ = r0 + (size_t)128*DD;
          dot2<4>(r0, r1_, xv, g, 0, a0, a1);
          a0 = red8(a0); a1 = red8(a1);
          if(!g){ gx[pp*256+gid] = a0; gx[pp*256+128+gid] = a1; }
        }
      }
      __syncthreads();
      // ---- phase C: route2 (24 outs, K=256) + S->f16 conversion
      {
        if(gid < NSL){
          const u16* row = r2T + (size_t)(li*NSL + gid)*DD;
          float acc = red8(dotg8(row, hmid, g, 4));
          if(!g) alpha[gid] = acc + b_r2[li*NSL+gid];
        }
        for(int i=tid; i<32*DD; i+=1024){
          int s_ = i>>8, d = i & (DD-1);
          sbf[s_*264+d] = (s_<NSL) ? f2h(Sl[s_*DD+d]) : (u16)0;
        }
      }
      __syncthreads();
      if(tid==0){ // softmax over 24 (TAU=1); consumed after phase-D barrier
        float m=-1e30f;
        for(int s_=0;s_<NSL;++s_) m = fmaxf(m, alpha[s_]);
        float sum=0.f;
        for(int s_=0;s_<NSL;++s_){ float e=__expf(alpha[s_]-m); alpha[s_]=e; sum+=e; }
        float inv = 1.f/sum;
        for(int s_=0;s_<NSL;++s_) alpha[s_]*=inv;
      }
      // ---- phase D: gh = S @ whh^T via mfma 16x16x32 f16 (16 waves, 3 tiles each)
      {
        const int l = tid & 63, w = tid >> 6;
        const int lr = l & 15, lk = l >> 4;
        const u16* WB = whhW + (size_t)li*3*DD*DD;
        const u16* a0p = sbf + lr*264 + lk*8;
        const u16* a1p = sbf + (16+lr)*264 + lk*8;
        for(int nt=w; nt<48; nt+=16){
          const u16* bp = WB + (size_t)(nt*16 + lr)*DD + lk*8;
          f32x4 acc0 = {0.f,0.f,0.f,0.f}, acc1 = {0.f,0.f,0.f,0.f};
          #pragma unroll
          for(int ks=0; ks<8; ++ks){
            f16x8 bfr = *(const f16x8*)(bp + ks*32);
            f16x8 a0  = *(const f16x8*)(a0p + ks*32);
            f16x8 a1  = *(const f16x8*)(a1p + ks*32);
            acc0 = __builtin_amdgcn_mfma_f32_16x16x32_f16(a0, bfr, acc0, 0,0,0);
            acc1 = __builtin_amdgcn_mfma_f32_16x16x32_f16(a1, bfr, acc1, 0,0,0);
          }
          #pragma unroll
          for(int r=0;r<4;++r){
            int s0 = lk*4 + r;                 // row=(lane>>4)*4+reg, col=lane&15
            gh16[s0*GHS + nt*16 + lr] = f2h(acc0[r]);
            int s1 = 16 + lk*4 + r;
            if(s1 < NSL) gh16[s1*GHS + nt*16 + lr] = f2h(acc1[r]);
          }
        }
      }
      __syncthreads();
      // ---- phase E: GRU update + slot_ctx partials (4 sub-banks of 256 threads)
      {
        int d = tid & (DD-1), so = tid >> 8;   // so in [0,4)
        const float* bihL = bih + li*3*DD;
        const float* bhhL = bhh + li*3*DD;
        float gir = gx[d], giz = gx[DD+d], gin = gx[2*DD+d];
        float bir = bihL[d], biz = bihL[DD+d], bin = bihL[2*DD+d];
        float bhr = bhhL[d], bhz = bhhL[DD+d], bhn = bhhL[2*DD+d];
        float pctx = 0.f;
        for(int j=0;j<NSL/4;++j){
          int s_ = 4*j + so;
          float al = alpha[s_];
          float hr = h2f(gh16[s_*GHS+d])      + bhr;
          float hz = h2f(gh16[s_*GHS+DD+d])   + bhz;
          float hn = h2f(gh16[s_*GHS+2*DD+d]) + bhn;
          float rr = sigm_f(al*gir + bir + hr);
          float zz = sigm_f(al*giz + biz + hz);
          float nn = tanh_f(al*gin + bin + rr*hn);
          float sv = Sl[s_*DD+d];
          float ns = (1.f-zz)*nn + zz*sv;
          Sl[s_*DD+d] = ns;
          pctx += al*ns;
        }
        pc[tid] = pctx;
      }
      __syncthreads();
      if(tid<DD) sctx[tid] = pc[tid] + pc[DD+tid] + pc[2*DD+tid] + pc[3*DD+tid];
      __syncthreads();
      // ---- phase F: proj [256 outs, K=256], rows gid and 128+gid
      {
        float aA=0.f, aB=0.f;
        const u16* rA = pjT + (size_t)(li*DD + gid)*DD;
        const u16* rB = rA + (size_t)128*DD;
        dot2<4>(rA, rB, sctx, g, 0, aA, aB);
        aA = red8(aA); aB = red8(aB);
        if(!g){
          xm[gid]     = xv[gid]     + b_pj[li*DD+gid]     + aA;
          xm[128+gid] = xv[128+gid] + b_pj[li*DD+128+gid] + aB;
        }
      }
      __syncthreads();
      // ---- LN1
      layernorm256(h1, xm, g1+li*DD, be1+li*DD, red, tid);
      // ---- ffn1 [512 outs, K=256], pairs (0,1),(2,3)
      {
        #pragma unroll
        for(int pp=0; pp<2; ++pp){
          float a0=0.f, a1=0.f;
          const u16* r0 = f1T + (size_t)(li*HH + pp*256 + gid)*DD;
          const u16* r1_ = r0 + (size_t)128*DD;
          dot2<4>(r0, r1_, h1, g, 0, a0, a1);
          a0 = red8(a0); a1 = red8(a1);
          if(!g){
            ff[pp*256+gid]     = gelu_f(a0 + b_f1[li*HH+pp*256+gid]);
            ff[pp*256+128+gid] = gelu_f(a1 + b_f1[li*HH+pp*256+128+gid]);
          }
        }
      }
      __syncthreads();
      // ---- ffn2 [256 outs, K=512], rows gid and 128+gid
      {
        float aA=0.f, aB=0.f;
        const u16* rA = f2T + (size_t)(li*DD + gid)*HH;
        const u16* rB = rA + (size_t)128*HH;
        dot2<4>(rA, rB, ff, g, 0,   aA, aB);
        dot2<4>(rA, rB, ff, g, 256, aA, aB);
        aA = red8(aA); aB = red8(aB);
        if(!g){
          xm[gid]     += b_f2[li*DD+gid]     + aA;
          xm[128+gid] += b_f2[li*DD+128+gid] + aB;
        }
      }
      __syncthreads();
      // ---- LN2 -> xv (next layer input)
      layernorm256(xv, xm, g2+li*DD, be2+li*DD, red, tid);
    } // layers

    // ---- head: LN + [96 x 256] GEMV, rows gid and 48+gid (groups 0..47)
    layernorm256(h1, xv, go, bo, red, tid);
    if(gid < 48){
      float aA=0.f, aB=0.f;
      dot2<4>(hdT + (size_t)gid*DD, hdT + (size_t)(48+gid)*DD, h1, g, 0, aA, aB);
      aA = red8(aA); aB = red8(aB);
      if(!g){
        float* outp = out + ((size_t)b*TT + t)*VV;
        outp[gid]    = aA + b_hd[gid];
        outp[48+gid] = aB + b_hd[48+gid];
      }
    }
    __syncthreads();
  }
}

extern "C" void kernel_launch(void* const* d_in, const int* in_sizes, int n_in,
                              void* d_out, int out_size, void* d_ws, size_t ws_size,
                              hipStream_t stream){
  const int*   x    = (const int*)  d_in[0];
  const float* emb  = (const float*)d_in[1];
  const float* pos  = (const float*)d_in[2];
  const float* r1   = (const float*)d_in[3];
  const float* br1  = (const float*)d_in[4];
  const float* r2   = (const float*)d_in[5];
  const float* br2  = (const float*)d_in[6];
  const float* wih  = (const float*)d_in[7];
  const float* whh  = (const float*)d_in[8];
  const float* bih  = (const float*)d_in[9];
  const float* bhh  = (const float*)d_in[10];
  const float* pj   = (const float*)d_in[11];
  const float* bpj  = (const float*)d_in[12];
  const float* g1   = (const float*)d_in[13];
  const float* be1  = (const float*)d_in[14];
  const float* f1   = (const float*)d_in[15];
  const float* bf1  = (const float*)d_in[16];
  const float* f2   = (const float*)d_in[17];
  const float* bf2  = (const float*)d_in[18];
  const float* g2   = (const float*)d_in[19];
  const float* be2  = (const float*)d_in[20];
  const float* go   = (const float*)d_in[21];
  const float* bo   = (const float*)d_in[22];
  const float* hd   = (const float*)d_in[23];
  const float* bhd  = (const float*)d_in[24];
  float* out = (float*)d_out;
  u16* ws = (u16*)d_ws;

  // f16 weight sections in workspace (element offsets)
  u16* r1T  = ws + 0;        // L*256*512
  u16* r2T  = ws + 262144;   // L*24*256
  u16* wihW = ws + 274432;   // L*768*256
  u16* whhW = ws + 667648;   // L*768*256
  u16* pjT  = ws + 1060864;  // L*256*256
  u16* f1T  = ws + 1191936;  // L*512*256
  u16* f2T  = ws + 1454080;  // L*256*512
  u16* hdT  = ws + 1716224;  // 96*256

  k_cvt<<<(2*768*256+255)/256,256,0,stream>>>(wih, wihW, 2*768*256);
  k_cvt<<<(2*768*256+255)/256,256,0,stream>>>(whh, whhW, 2*768*256);
  for(int li=0; li<2; ++li){
    k_cvtT<<<(512*256+255)/256,256,0,stream>>>(r1 + li*512*256, r1T + li*256*512, 512, 256);
    k_cvtT<<<(256*24+255)/256, 256,0,stream>>>(r2 + li*256*24,  r2T + li*24*256,  256, 24);
    k_cvtT<<<(256*256+255)/256,256,0,stream>>>(pj + li*256*256, pjT + li*256*256, 256, 256);
    k_cvtT<<<(256*512+255)/256,256,0,stream>>>(f1 + li*256*512, f1T + li*512*256, 256, 512);
    k_cvtT<<<(512*256+255)/256,256,0,stream>>>(f2 + li*512*256, f2T + li*256*512, 512, 256);
  }
  k_cvtT<<<(256*96+255)/256,256,0,stream>>>(hd, hdT, 256, 96);

  const int smem = 30016*4;
  hipFuncSetAttribute(reinterpret_cast<const void*>(ssr_main),
                      hipFuncAttributeMaxDynamicSharedMemorySize, smem);
  ssr_main<<<BB, 1024, smem, stream>>>(x, emb, pos, r1T, br1, r2T, br2, wihW, whhW, bih, bhh,
                                       pjT, bpj, g1, be1, f1T, bf1, f2T, bf2, g2, be2, go, bo,
                                       hdT, bhd, out);
}